// Round 1
// baseline (310.378 us; speedup 1.0000x reference)
//
#include <hip/hip_runtime.h>
#include <hip/hip_bf16.h>

typedef unsigned short u16;
typedef unsigned int u32;
typedef __attribute__((ext_vector_type(8))) short short8;
typedef __attribute__((ext_vector_type(4))) float f32x4;

#define B_ 4
#define T_ 1024
#define M_ 1024
#define E_ 1024
#define NH 16
#define DH 64
#define HD 1024
#define JTOT 2048
#define SCALE 0.125f

// ---------- helpers ----------
__device__ __forceinline__ u16 f2b(float f) {
  u32 x = __float_as_uint(f);
  u32 r = (x + 0x7fffu + ((x >> 16) & 1u)) >> 16;  // RNE
  return (u16)r;
}

__device__ __forceinline__ void gload_lds16(const void* g, void* l) {
  __builtin_amdgcn_global_load_lds((const __attribute__((address_space(1))) u32*)g,
                                   (__attribute__((address_space(3))) u32*)l, 16, 0, 0);
}

// ---------- conversion kernels ----------
__global__ __launch_bounds__(256) void cvt_bf16(const float* __restrict__ in,
                                                u16* __restrict__ out, int n8) {
  int i = blockIdx.x * 256 + threadIdx.x;
  if (i >= n8) return;
  const float4* p = (const float4*)in + (size_t)i * 2;
  float4 f0 = p[0], f1 = p[1];
  short8 o;
  o[0] = (short)f2b(f0.x); o[1] = (short)f2b(f0.y);
  o[2] = (short)f2b(f0.z); o[3] = (short)f2b(f0.w);
  o[4] = (short)f2b(f1.x); o[5] = (short)f2b(f1.y);
  o[6] = (short)f2b(f1.z); o[7] = (short)f2b(f1.w);
  ((short8*)out)[i] = o;
}

// W [1024][1024] f32 row-major -> WT [1024][1024] bf16 (transposed)
__global__ __launch_bounds__(256) void cvt_wT(const float* __restrict__ W,
                                              u16* __restrict__ WT) {
  __shared__ float tile[64][65];
  int t = threadIdx.x;
  int r0 = blockIdx.y * 64, c0 = blockIdx.x * 64;
#pragma unroll
  for (int i = 0; i < 16; ++i) {
    int r = i * 4 + (t >> 6), c = t & 63;
    tile[r][c] = W[(size_t)(r0 + r) * 1024 + c0 + c];
  }
  __syncthreads();
#pragma unroll
  for (int i = 0; i < 16; ++i) {
    int r = i * 4 + (t >> 6), c = t & 63;
    WT[(size_t)(c0 + r) * 1024 + r0 + c] = f2b(tile[c][r]);
  }
}

// xl_memory [B][M][2][HD] f32 -> kb/vb rows 0..1023 (bf16)
__global__ __launch_bounds__(256) void cvt_xl(const float* __restrict__ xl,
                                              u16* __restrict__ kb, u16* __restrict__ vb) {
  int i = blockIdx.x * 256 + threadIdx.x;  // [0, 1048576)
  int hd8 = i & 127, s = (i >> 7) & 1, j = (i >> 8) & 1023, b = i >> 18;
  const float4* p = (const float4*)(xl + ((((size_t)b * 1024 + j) * 2 + s) * 1024 + (size_t)hd8 * 8));
  float4 f0 = p[0], f1 = p[1];
  short8 o;
  o[0] = (short)f2b(f0.x); o[1] = (short)f2b(f0.y);
  o[2] = (short)f2b(f0.z); o[3] = (short)f2b(f0.w);
  o[4] = (short)f2b(f1.x); o[5] = (short)f2b(f1.y);
  o[6] = (short)f2b(f1.z); o[7] = (short)f2b(f1.w);
  u16* dst = (s == 0 ? kb : vb) + ((size_t)b * JTOT + j) * HD + (size_t)hd8 * 8;
  *(short8*)dst = o;
}

// ---------- 128x128 bf16 MFMA GEMM (m97-style), MODE 0 = QKV, MODE 1 = out-proj ----------
template <int MODE>
__global__ __launch_bounds__(256) void gemm128(
    const u16* __restrict__ A, const u16* __restrict__ BT,
    const float* __restrict__ b0, const float* __restrict__ b1, const float* __restrict__ b2,
    u16* __restrict__ qb, float* __restrict__ kvout, u16* __restrict__ kb, u16* __restrict__ vb,
    float* __restrict__ outf, int Ntiles, int Kdim) {
  __shared__ __align__(16) u16 As[128 * 32];
  __shared__ __align__(16) u16 Bs[128 * 32];
  const int t = threadIdx.x;
  const int lane = t & 63, wv = t >> 6;
  const int wr = wv >> 1, wc = wv & 1;
  const int m0 = (blockIdx.x / Ntiles) * 128;
  const int n0 = (blockIdx.x % Ntiles) * 128;
  const int lr = lane & 15, lg = lane >> 4;

  f32x4 acc[4][4] = {};

  for (int kc = 0; kc < Kdim; kc += 32) {
    __syncthreads();  // previous compute done before overwrite
#pragma unroll
    for (int i = 0; i < 2; ++i) {
      int p = t + 256 * i;
      gload_lds16(A + (size_t)(m0 + (p >> 2)) * Kdim + kc + (p & 3) * 8, &As[p * 8]);
    }
#pragma unroll
    for (int i = 0; i < 2; ++i) {
      int p = t + 256 * i;
      gload_lds16(BT + (size_t)(n0 + (p >> 2)) * Kdim + kc + (p & 3) * 8, &Bs[p * 8]);
    }
    __syncthreads();  // staging visible (barrier drains vmcnt)

    short8 af[4], bf[4];
#pragma unroll
    for (int mf = 0; mf < 4; ++mf)
      af[mf] = *(const short8*)&As[(wr * 64 + mf * 16 + lr) * 32 + lg * 8];
#pragma unroll
    for (int nf = 0; nf < 4; ++nf)
      bf[nf] = *(const short8*)&Bs[(wc * 64 + nf * 16 + lr) * 32 + lg * 8];
#pragma unroll
    for (int mf = 0; mf < 4; ++mf)
#pragma unroll
      for (int nf = 0; nf < 4; ++nf)
        acc[mf][nf] = __builtin_amdgcn_mfma_f32_16x16x32_bf16(af[mf], bf[nf], acc[mf][nf], 0, 0, 0);
  }

#pragma unroll
  for (int mf = 0; mf < 4; ++mf) {
#pragma unroll
    for (int nf = 0; nf < 4; ++nf) {
#pragma unroll
      for (int r = 0; r < 4; ++r) {
        int row = m0 + wr * 64 + mf * 16 + lg * 4 + r;
        int col = n0 + wc * 64 + nf * 16 + lr;
        float v = acc[mf][nf][r];
        if (MODE == 0) {
          int b = row >> 10, tt = row & 1023;
          if (col < 1024) {
            v += b0[col];
            qb[(size_t)row * HD + col] = f2b(v * SCALE);
          } else if (col < 2048) {
            int hd = col - 1024;
            v += b1[hd];
            kvout[((size_t)(b * 1024 + tt) * 2 + 0) * HD + hd] = v;
            kb[((size_t)b * JTOT + 1024 + tt) * HD + hd] = f2b(v);
          } else {
            int hd = col - 2048;
            v += b2[hd];
            kvout[((size_t)(b * 1024 + tt) * 2 + 1) * HD + hd] = v;
            vb[((size_t)b * JTOT + 1024 + tt) * HD + hd] = f2b(v);
          }
        } else {
          outf[(size_t)row * E_ + col] = v + b0[col];
        }
      }
    }
  }
}

// ---------- flash attention: block = (b, h, 64-row q-tile), 4 waves x 16 rows ----------
__global__ __launch_bounds__(256) void attn_kernel(
    const u16* __restrict__ qb, const u16* __restrict__ kb, const u16* __restrict__ vb,
    const float* __restrict__ rel, u16* __restrict__ aout) {
  __shared__ __align__(16) u16 Pl[64 * 72];
  __shared__ __align__(16) u16 Vt[64 * 72];
  const int bx = blockIdx.x;
  const int qt = bx & 15, h = (bx >> 4) & 15, b = bx >> 8;
  const int i0 = qt * 64;
  const int t = threadIdx.x, lane = t & 63, w = t >> 6;
  const int lr = lane & 15, lg = lane >> 4;

  const u16* kbase = kb + (size_t)b * JTOT * HD + h * 64;
  const u16* vbase = vb + (size_t)b * JTOT * HD + h * 64;
  const float* relbase = rel + (size_t)h * T_ * JTOT;

  short8 qf[2];
#pragma unroll
  for (int kc = 0; kc < 2; ++kc)
    qf[kc] = *(const short8*)&qb[(size_t)(b * T_ + i0 + w * 16 + lr) * HD + h * 64 + kc * 32 + lg * 8];

  f32x4 o[4] = {};
  float mrow[4], lrow[4];
#pragma unroll
  for (int r = 0; r < 4; ++r) { mrow[r] = -__builtin_inff(); lrow[r] = 0.f; }

  const int nchunks = qt + 17;  // causal skip: j <= i+M only
  for (int jc = 0; jc < nchunks; ++jc) {
    const int j0 = jc * 64;
    __syncthreads();  // prev PV done reading Vt/Pl
    // stage V^T into LDS: Vt[d][key], padded stride 72
    {
      int vr = t >> 2, c0 = (t & 3) * 16;
      const u16* src = vbase + (size_t)(j0 + vr) * HD + c0;
      short8 v0 = *(const short8*)src;
      short8 v1 = *(const short8*)(src + 8);
#pragma unroll
      for (int e = 0; e < 8; ++e) {
        Vt[(c0 + e) * 72 + vr] = ((const u16*)&v0)[e];
        Vt[(c0 + 8 + e) * 72 + vr] = ((const u16*)&v1)[e];
      }
    }
    // S = Q K^T  (16 q-rows per wave x 64 keys)
    f32x4 s[4] = {};
#pragma unroll
    for (int nf = 0; nf < 4; ++nf)
#pragma unroll
      for (int kc = 0; kc < 2; ++kc) {
        short8 kf = *(const short8*)&kbase[(size_t)(j0 + nf * 16 + lr) * HD + kc * 32 + lg * 8];
        s[nf] = __builtin_amdgcn_mfma_f32_16x16x32_bf16(qf[kc], kf, s[nf], 0, 0, 0);
      }
    // logits = (rel + S)*SCALE, causal mask, online softmax
    float p[4][4];
    float chmax[4];
#pragma unroll
    for (int r = 0; r < 4; ++r) chmax[r] = -__builtin_inff();
    const int ib = i0 + w * 16 + lg * 4;
#pragma unroll
    for (int nf = 0; nf < 4; ++nf)
#pragma unroll
      for (int r = 0; r < 4; ++r) {
        int i = ib + r, j = j0 + nf * 16 + lr;
        float v = (relbase[(size_t)i * JTOT + j] + s[nf][r]) * SCALE;
        if (j > i + M_) v = -__builtin_inff();
        p[nf][r] = v;
        chmax[r] = fmaxf(chmax[r], v);
      }
#pragma unroll
    for (int msk = 1; msk <= 8; msk <<= 1)
#pragma unroll
      for (int r = 0; r < 4; ++r)
        chmax[r] = fmaxf(chmax[r], __shfl_xor(chmax[r], msk, 64));
    float sc[4], chs[4];
#pragma unroll
    for (int r = 0; r < 4; ++r) {
      float nm = fmaxf(mrow[r], chmax[r]);
      sc[r] = __expf(mrow[r] - nm);
      mrow[r] = nm;
      chs[r] = 0.f;
    }
#pragma unroll
    for (int nf = 0; nf < 4; ++nf)
#pragma unroll
      for (int r = 0; r < 4; ++r) {
        float pe = __expf(p[nf][r] - mrow[r]);
        p[nf][r] = pe;
        chs[r] += pe;
      }
#pragma unroll
    for (int msk = 1; msk <= 8; msk <<= 1)
#pragma unroll
      for (int r = 0; r < 4; ++r)
        chs[r] += __shfl_xor(chs[r], msk, 64);
#pragma unroll
    for (int r = 0; r < 4; ++r) lrow[r] = lrow[r] * sc[r] + chs[r];
#pragma unroll
    for (int nf = 0; nf < 4; ++nf)
#pragma unroll
      for (int r = 0; r < 4; ++r) o[nf][r] *= sc[r];
    // write P (each wave writes its own 16 rows; also covers Vt visibility)
#pragma unroll
    for (int nf = 0; nf < 4; ++nf)
#pragma unroll
      for (int r = 0; r < 4; ++r)
        Pl[(w * 16 + lg * 4 + r) * 72 + nf * 16 + lr] = f2b(p[nf][r]);
    __syncthreads();
    // O += P @ V
#pragma unroll
    for (int kc = 0; kc < 2; ++kc) {
      short8 pa = *(const short8*)&Pl[(w * 16 + lr) * 72 + kc * 32 + lg * 8];
#pragma unroll
      for (int nf = 0; nf < 4; ++nf) {
        short8 vf = *(const short8*)&Vt[(nf * 16 + lr) * 72 + kc * 32 + lg * 8];
        o[nf] = __builtin_amdgcn_mfma_f32_16x16x32_bf16(pa, vf, o[nf], 0, 0, 0);
      }
    }
  }
  // epilogue: normalize and store bf16 [b][t][h*64+d]
  float inv[4];
#pragma unroll
  for (int r = 0; r < 4; ++r) inv[r] = 1.0f / lrow[r];
#pragma unroll
  for (int nf = 0; nf < 4; ++nf)
#pragma unroll
    for (int r = 0; r < 4; ++r) {
      int i = i0 + w * 16 + lg * 4 + r, d = nf * 16 + lr;
      aout[(size_t)(b * T_ + i) * HD + h * 64 + d] = f2b(o[nf][r] * inv[r]);
    }
}

// ---------- launch ----------
extern "C" void kernel_launch(void* const* d_in, const int* in_sizes, int n_in,
                              void* d_out, int out_size, void* d_ws, size_t ws_size,
                              hipStream_t stream) {
  const float* x  = (const float*)d_in[0];
  const float* xl = (const float*)d_in[1];
  const float* rel = (const float*)d_in[2];
  const float* Wq = (const float*)d_in[3];
  const float* bq = (const float*)d_in[4];
  const float* Wk = (const float*)d_in[5];
  const float* bk = (const float*)d_in[6];
  const float* Wv = (const float*)d_in[7];
  const float* bv = (const float*)d_in[8];
  const float* Wo = (const float*)d_in[9];
  const float* bo = (const float*)d_in[10];

  float* out = (float*)d_out;
  float* kvout = out + (size_t)B_ * T_ * E_;

  char* ws = (char*)d_ws;
  u16* xb    = (u16*)ws; ws += (size_t)4096 * 1024 * 2;
  u16* wqkvT = (u16*)ws; ws += (size_t)3072 * 1024 * 2;
  u16* woT   = (u16*)ws; ws += (size_t)1024 * 1024 * 2;
  u16* qbuf  = (u16*)ws; ws += (size_t)4096 * 1024 * 2;
  u16* kb    = (u16*)ws; ws += (size_t)B_ * JTOT * 1024 * 2;
  u16* vb    = (u16*)ws; ws += (size_t)B_ * JTOT * 1024 * 2;
  u16* aout  = (u16*)ws; ws += (size_t)4096 * 1024 * 2;

  cvt_bf16<<<2048, 256, 0, stream>>>(x, xb, 524288);
  dim3 tg(16, 16);
  cvt_wT<<<tg, 256, 0, stream>>>(Wq, wqkvT);
  cvt_wT<<<tg, 256, 0, stream>>>(Wk, wqkvT + (size_t)1024 * 1024);
  cvt_wT<<<tg, 256, 0, stream>>>(Wv, wqkvT + (size_t)2048 * 1024);
  cvt_wT<<<tg, 256, 0, stream>>>(Wo, woT);
  cvt_xl<<<4096, 256, 0, stream>>>(xl, kb, vb);

  gemm128<0><<<32 * 24, 256, 0, stream>>>(xb, wqkvT, bq, bk, bv,
                                          qbuf, kvout, kb, vb, nullptr, 24, 1024);
  attn_kernel<<<B_ * NH * 16, 256, 0, stream>>>(qbuf, kb, vb, rel, aout);
  gemm128<1><<<32 * 8, 256, 0, stream>>>(aout, woT, bo, nullptr, nullptr,
                                         nullptr, nullptr, nullptr, nullptr, out, 8, 1024);
}

// Round 2
// 278.382 us; speedup vs baseline: 1.1149x; 1.1149x over previous
//
#include <hip/hip_runtime.h>
#include <hip/hip_bf16.h>

typedef unsigned short u16;
typedef unsigned int u32;
typedef __attribute__((ext_vector_type(8))) short short8;
typedef __attribute__((ext_vector_type(4))) float f32x4;

#define B_ 4
#define T_ 1024
#define E_ 1024
#define NH 16
#define HD 1024
#define JTOT 2048
#define SCALE 0.125f

// ---------- helpers ----------
__device__ __forceinline__ u16 f2b(float f) {
  u32 x = __float_as_uint(f);
  u32 r = (x + 0x7fffu + ((x >> 16) & 1u)) >> 16;  // RNE
  return (u16)r;
}

__device__ __forceinline__ void gload_lds16(const void* g, void* l) {
  __builtin_amdgcn_global_load_lds((const __attribute__((address_space(1))) u32*)g,
                                   (__attribute__((address_space(3))) u32*)l, 16, 0, 0);
}

__device__ __forceinline__ short8 pack8(float4 f0, float4 f1) {
  short8 o;
  o[0] = (short)f2b(f0.x); o[1] = (short)f2b(f0.y);
  o[2] = (short)f2b(f0.z); o[3] = (short)f2b(f0.w);
  o[4] = (short)f2b(f1.x); o[5] = (short)f2b(f1.y);
  o[6] = (short)f2b(f1.z); o[7] = (short)f2b(f1.w);
  return o;
}

// ---------- conversion kernels ----------
__global__ __launch_bounds__(256) void cvt_bf16(const float* __restrict__ in,
                                                u16* __restrict__ out, int n8) {
  int i = blockIdx.x * 256 + threadIdx.x;
  if (i >= n8) return;
  const float4* p = (const float4*)in + (size_t)i * 2;
  ((short8*)out)[i] = pack8(p[0], p[1]);
}

// fused 4x: W [1024][1024] f32 -> WT bf16 transposed
__global__ __launch_bounds__(256) void cvt_w4T(const float* __restrict__ Wq, const float* __restrict__ Wk,
                                               const float* __restrict__ Wv, const float* __restrict__ Wo,
                                               u16* __restrict__ wqkvT, u16* __restrict__ woT) {
  __shared__ float tile[64][65];
  const float* W;
  u16* WT;
  int z = blockIdx.z;
  if (z == 0) { W = Wq; WT = wqkvT; }
  else if (z == 1) { W = Wk; WT = wqkvT + (size_t)1024 * 1024; }
  else if (z == 2) { W = Wv; WT = wqkvT + (size_t)2048 * 1024; }
  else { W = Wo; WT = woT; }
  int t = threadIdx.x;
  int r0 = blockIdx.y * 64, c0 = blockIdx.x * 64;
#pragma unroll
  for (int i = 0; i < 16; ++i) {
    int r = i * 4 + (t >> 6), c = t & 63;
    tile[r][c] = W[(size_t)(r0 + r) * 1024 + c0 + c];
  }
  __syncthreads();
#pragma unroll
  for (int i = 0; i < 16; ++i) {
    int r = i * 4 + (t >> 6), c = t & 63;
    WT[(size_t)(c0 + r) * 1024 + r0 + c] = f2b(tile[c][r]);
  }
}

// xl k-half -> kt tiles [B][H][jc 0..15][64 j][64 d ^ swz] bf16
__global__ __launch_bounds__(256) void cvt_xl_k(const float* __restrict__ xl, u16* __restrict__ kt) {
  int i = blockIdx.x * 256 + threadIdx.x;  // [0, 524288)
  int hd8 = i & 127, j = (i >> 7) & 1023, b = i >> 17;
  const float4* p = (const float4*)(xl + ((((size_t)b * 1024 + j) * 2 + 0) * 1024 + (size_t)hd8 * 8));
  short8 o = pack8(p[0], p[1]);
  int h = hd8 >> 3, d0 = (hd8 & 7) * 8;
  int jc = j >> 6, jl = j & 63;
  u16* dst = kt + (((size_t)(b * 16 + h) * 32 + jc) * 4096) + jl * 64 + (d0 ^ (((jl >> 2) & 3) << 4));
  *(short8*)dst = o;
}

// xl v-half -> vt tiles [B][H][jc 0..15][64 d][64 j ^ swz] bf16 (transposed)
__global__ __launch_bounds__(256) void cvt_xl_vT(const float* __restrict__ xl, u16* __restrict__ vt) {
  __shared__ u16 Vl[64 * 72];
  int bx = blockIdx.x;
  int jc = bx & 15, h = (bx >> 4) & 15, b = bx >> 8;
  int t = threadIdx.x;
  int j0 = jc * 64;
#pragma unroll
  for (int it = 0; it < 2; ++it) {
    int p = t + 256 * it;
    int j = p >> 3, d8 = p & 7;
    const float4* src = (const float4*)(xl + ((((size_t)b * 1024 + j0 + j) * 2 + 1) * 1024 + h * 64 + (size_t)d8 * 8));
    *(short8*)&Vl[j * 72 + d8 * 8] = pack8(src[0], src[1]);
  }
  __syncthreads();
#pragma unroll
  for (int it = 0; it < 2; ++it) {
    int p = t + 256 * it;
    int d = p >> 3, j8 = p & 7;
    short8 o;
#pragma unroll
    for (int e = 0; e < 8; ++e) o[e] = (short)Vl[(j8 * 8 + e) * 72 + d];
    u16* dst = vt + (((size_t)(b * 16 + h) * 32 + jc) * 4096) + d * 64 + ((j8 * 8) ^ (((d >> 2) & 3) << 4));
    *(short8*)dst = o;
  }
}

// vb_new [b][tt][hd] bf16 -> vt tiles jc 16..31 (transposed + swizzled)
__global__ __launch_bounds__(256) void trans_vnew(const u16* __restrict__ vb, u16* __restrict__ vt) {
  __shared__ u16 Vl[64 * 72];
  int bx = blockIdx.x;
  int jcl = bx & 15, h = (bx >> 4) & 15, b = bx >> 8;
  int jc = 16 + jcl;
  int t = threadIdx.x;
  int t0 = jcl * 64;  // token base within [0,1024)
#pragma unroll
  for (int it = 0; it < 2; ++it) {
    int p = t + 256 * it;
    int j = p >> 3, d8 = p & 7;
    *(short8*)&Vl[j * 72 + d8 * 8] =
        *(const short8*)&vb[((size_t)b * 1024 + t0 + j) * 1024 + h * 64 + d8 * 8];
  }
  __syncthreads();
#pragma unroll
  for (int it = 0; it < 2; ++it) {
    int p = t + 256 * it;
    int d = p >> 3, j8 = p & 7;
    short8 o;
#pragma unroll
    for (int e = 0; e < 8; ++e) o[e] = (short)Vl[(j8 * 8 + e) * 72 + d];
    u16* dst = vt + (((size_t)(b * 16 + h) * 32 + jc) * 4096) + d * 64 + ((j8 * 8) ^ (((d >> 2) & 3) << 4));
    *(short8*)dst = o;
  }
}

// ---------- 128x128 bf16 MFMA GEMM, MODE 0 = QKV, MODE 1 = out-proj ----------
template <int MODE>
__global__ __launch_bounds__(256) void gemm128(
    const u16* __restrict__ A, const u16* __restrict__ BT,
    const float* __restrict__ b0, const float* __restrict__ b1, const float* __restrict__ b2,
    u16* __restrict__ qb, float* __restrict__ kvout, u16* __restrict__ kt, u16* __restrict__ vb,
    float* __restrict__ outf, int Ntiles, int Kdim) {
  __shared__ __align__(16) u16 As[128 * 32];
  __shared__ __align__(16) u16 Bs[128 * 32];
  const int t = threadIdx.x;
  const int lane = t & 63, wv = t >> 6;
  const int wr = wv >> 1, wc = wv & 1;
  const int m0 = (blockIdx.x / Ntiles) * 128;
  const int n0 = (blockIdx.x % Ntiles) * 128;
  const int lr = lane & 15, lg = lane >> 4;

  f32x4 acc[4][4] = {};

  for (int kc = 0; kc < Kdim; kc += 32) {
    __syncthreads();
#pragma unroll
    for (int i = 0; i < 2; ++i) {
      int p = t + 256 * i;
      gload_lds16(A + (size_t)(m0 + (p >> 2)) * Kdim + kc + (p & 3) * 8, &As[p * 8]);
    }
#pragma unroll
    for (int i = 0; i < 2; ++i) {
      int p = t + 256 * i;
      gload_lds16(BT + (size_t)(n0 + (p >> 2)) * Kdim + kc + (p & 3) * 8, &Bs[p * 8]);
    }
    __syncthreads();

    short8 af[4], bf[4];
#pragma unroll
    for (int mf = 0; mf < 4; ++mf)
      af[mf] = *(const short8*)&As[(wr * 64 + mf * 16 + lr) * 32 + lg * 8];
#pragma unroll
    for (int nf = 0; nf < 4; ++nf)
      bf[nf] = *(const short8*)&Bs[(wc * 64 + nf * 16 + lr) * 32 + lg * 8];
#pragma unroll
    for (int mf = 0; mf < 4; ++mf)
#pragma unroll
      for (int nf = 0; nf < 4; ++nf)
        acc[mf][nf] = __builtin_amdgcn_mfma_f32_16x16x32_bf16(af[mf], bf[nf], acc[mf][nf], 0, 0, 0);
  }

#pragma unroll
  for (int mf = 0; mf < 4; ++mf) {
#pragma unroll
    for (int nf = 0; nf < 4; ++nf) {
#pragma unroll
      for (int r = 0; r < 4; ++r) {
        int row = m0 + wr * 64 + mf * 16 + lg * 4 + r;
        int col = n0 + wc * 64 + nf * 16 + lr;
        float v = acc[mf][nf][r];
        if (MODE == 0) {
          int b = row >> 10, tt = row & 1023;
          if (col < 1024) {
            v += b0[col];
            qb[(size_t)row * HD + col] = f2b(v * (SCALE * SCALE));  // both scales folded
          } else if (col < 2048) {
            int hd = col - 1024;
            v += b1[hd];
            kvout[((size_t)(b * 1024 + tt) * 2 + 0) * HD + hd] = v;
            int h = hd >> 6, d = hd & 63, jl = tt & 63, jc = 16 + (tt >> 6);
            kt[(((size_t)(b * 16 + h) * 32 + jc) * 4096) + jl * 64 + (d ^ (((jl >> 2) & 3) << 4))] = f2b(v);
          } else {
            int hd = col - 2048;
            v += b2[hd];
            kvout[((size_t)(b * 1024 + tt) * 2 + 1) * HD + hd] = v;
            vb[((size_t)b * 1024 + tt) * 1024 + hd] = f2b(v);
          }
        } else {
          outf[(size_t)row * E_ + col] = v + b0[col];
        }
      }
    }
  }
}

// ---------- flash attention: block = (b, h, 64-row q-tile), 4 waves x 16 rows ----------
__global__ __launch_bounds__(256) void attn_kernel(
    const u16* __restrict__ qb, const u16* __restrict__ kt, const u16* __restrict__ vt,
    const float* __restrict__ rel, u16* __restrict__ aout) {
  __shared__ __align__(16) u16 Ks[2][4096];
  __shared__ __align__(16) u16 Vs[2][4096];
  __shared__ __align__(16) u16 Pl[4096];
  const int bx = blockIdx.x;
  const int qt = 15 - (bx & 15), h = (bx >> 4) & 15, b = bx >> 8;  // heavy tiles first
  const int i0 = qt * 64;
  const int t = threadIdx.x, lane = t & 63, w = t >> 6;
  const int lr = lane & 15, lg = lane >> 4;
  const int sel = (lr >> 2) & 3;

  const u16* ktb = kt + (size_t)(b * 16 + h) * 32 * 4096;
  const u16* vtb = vt + (size_t)(b * 16 + h) * 32 * 4096;
  const float* relbase = rel + (size_t)h * T_ * JTOT;
  const int ib = i0 + w * 16 + lg * 4;

  short8 qf[2];
#pragma unroll
  for (int kc = 0; kc < 2; ++kc)
    qf[kc] = *(const short8*)&qb[(size_t)(b * T_ + i0 + w * 16 + lr) * HD + h * 64 + kc * 32 + lg * 8];

  const int nchunks = qt + 17;

  auto stage = [&](int buf, int jc2) {
    const u16* ksrc = ktb + (size_t)jc2 * 4096;
    const u16* vsrc = vtb + (size_t)jc2 * 4096;
    gload_lds16(ksrc + t * 8, &Ks[buf][t * 8]);
    gload_lds16(ksrc + (t + 256) * 8, &Ks[buf][(t + 256) * 8]);
    gload_lds16(vsrc + t * 8, &Vs[buf][t * 8]);
    gload_lds16(vsrc + (t + 256) * 8, &Vs[buf][(t + 256) * 8]);
  };

  float rl[4][4];
  auto loadrel = [&](int j0) {
#pragma unroll
    for (int nf = 0; nf < 4; ++nf)
#pragma unroll
      for (int r = 0; r < 4; ++r)
        rl[nf][r] = relbase[(size_t)(ib + r) * JTOT + j0 + nf * 16 + lr];
  };

  stage(0, 0);
  loadrel(0);

  f32x4 o[4] = {};
  float mrow[4], lrow[4];
#pragma unroll
  for (int r = 0; r < 4; ++r) { mrow[r] = -__builtin_inff(); lrow[r] = 0.f; }

  int cur = 0;
  for (int jc = 0; jc < nchunks; ++jc) {
    __syncthreads();  // own vmcnt drained -> Ks/Vs[cur] staged, rl loaded; waves aligned
    if (jc + 1 < nchunks) stage(cur ^ 1, jc + 1);

    // S = Q K^T
    f32x4 s4[4] = {};
#pragma unroll
    for (int nf = 0; nf < 4; ++nf)
#pragma unroll
      for (int kc = 0; kc < 2; ++kc) {
        short8 kf = *(const short8*)&Ks[cur][(nf * 16 + lr) * 64 + ((kc * 32 + lg * 8) ^ (sel << 4))];
        s4[nf] = __builtin_amdgcn_mfma_f32_16x16x32_bf16(qf[kc], kf, s4[nf], 0, 0, 0);
      }

    // logits (q pre-scaled by SCALE^2, rel * SCALE)
    float p[4][4], chmax[4];
#pragma unroll
    for (int r = 0; r < 4; ++r) chmax[r] = -__builtin_inff();
    const bool domask = (jc == qt + 16);
#pragma unroll
    for (int nf = 0; nf < 4; ++nf)
#pragma unroll
      for (int r = 0; r < 4; ++r) {
        float v = fmaf(rl[nf][r], SCALE, s4[nf][r]);
        if (domask && (nf * 16 + lr) > (w * 16 + lg * 4 + r)) v = -__builtin_inff();
        p[nf][r] = v;
        chmax[r] = fmaxf(chmax[r], v);
      }
    if (jc + 1 < nchunks) loadrel((jc + 1) * 64);  // T14: issue early, consumed next iter

#pragma unroll
    for (int msk = 1; msk <= 8; msk <<= 1)
#pragma unroll
      for (int r = 0; r < 4; ++r)
        chmax[r] = fmaxf(chmax[r], __shfl_xor(chmax[r], msk, 64));

    float need = -__builtin_inff();
#pragma unroll
    for (int r = 0; r < 4; ++r) need = fmaxf(need, chmax[r] - mrow[r]);
    const bool dores = !__all(need <= 8.0f);  // T13 defer-max
    float sc[4];
    if (dores) {
#pragma unroll
      for (int r = 0; r < 4; ++r) {
        float nm = fmaxf(mrow[r], chmax[r]);
        sc[r] = __expf(mrow[r] - nm);
        mrow[r] = nm;
      }
    }
    float chs[4] = {0.f, 0.f, 0.f, 0.f};
#pragma unroll
    for (int nf = 0; nf < 4; ++nf)
#pragma unroll
      for (int r = 0; r < 4; ++r) {
        float pe = __expf(p[nf][r] - mrow[r]);
        chs[r] += pe;
        Pl[(w * 16 + lg * 4 + r) * 64 + (((nf ^ lg) << 4) + lr)] = f2b(pe);  // swizzled, conflict-free
      }
#pragma unroll
    for (int msk = 1; msk <= 8; msk <<= 1)
#pragma unroll
      for (int r = 0; r < 4; ++r)
        chs[r] += __shfl_xor(chs[r], msk, 64);
    if (dores) {
#pragma unroll
      for (int r = 0; r < 4; ++r) lrow[r] = lrow[r] * sc[r] + chs[r];
#pragma unroll
      for (int nf = 0; nf < 4; ++nf)
#pragma unroll
        for (int r = 0; r < 4; ++r) o[nf][r] *= sc[r];
    } else {
#pragma unroll
      for (int r = 0; r < 4; ++r) lrow[r] += chs[r];
    }

    // O += P @ V   (Pl is wave-private: no barrier needed)
#pragma unroll
    for (int kc = 0; kc < 2; ++kc) {
      const int pcol = (kc * 32 + lg * 8) ^ (sel << 4);
      short8 pa = *(const short8*)&Pl[(w * 16 + lr) * 64 + pcol];
#pragma unroll
      for (int nf = 0; nf < 4; ++nf) {
        short8 vf = *(const short8*)&Vs[cur][(nf * 16 + lr) * 64 + pcol];
        o[nf] = __builtin_amdgcn_mfma_f32_16x16x32_bf16(pa, vf, o[nf], 0, 0, 0);
      }
    }
    cur ^= 1;
  }

  float inv[4];
#pragma unroll
  for (int r = 0; r < 4; ++r) inv[r] = 1.0f / lrow[r];
#pragma unroll
  for (int nf = 0; nf < 4; ++nf)
#pragma unroll
    for (int r = 0; r < 4; ++r) {
      int i = i0 + w * 16 + lg * 4 + r, d = nf * 16 + lr;
      aout[(size_t)(b * T_ + i) * HD + h * 64 + d] = f2b(o[nf][r] * inv[r]);
    }
}

// ---------- launch ----------
extern "C" void kernel_launch(void* const* d_in, const int* in_sizes, int n_in,
                              void* d_out, int out_size, void* d_ws, size_t ws_size,
                              hipStream_t stream) {
  const float* x  = (const float*)d_in[0];
  const float* xl = (const float*)d_in[1];
  const float* rel = (const float*)d_in[2];
  const float* Wq = (const float*)d_in[3];
  const float* bq = (const float*)d_in[4];
  const float* Wk = (const float*)d_in[5];
  const float* bk = (const float*)d_in[6];
  const float* Wv = (const float*)d_in[7];
  const float* bv = (const float*)d_in[8];
  const float* Wo = (const float*)d_in[9];
  const float* bo = (const float*)d_in[10];

  float* out = (float*)d_out;
  float* kvout = out + (size_t)B_ * T_ * E_;

  char* ws = (char*)d_ws;
  u16* xb    = (u16*)ws; ws += (size_t)4096 * 1024 * 2;
  u16* wqkvT = (u16*)ws; ws += (size_t)3072 * 1024 * 2;
  u16* woT   = (u16*)ws; ws += (size_t)1024 * 1024 * 2;
  u16* qbuf  = (u16*)ws; ws += (size_t)4096 * 1024 * 2;
  u16* kt    = (u16*)ws; ws += (size_t)B_ * NH * 32 * 4096 * 2;
  u16* vt    = (u16*)ws; ws += (size_t)B_ * NH * 32 * 4096 * 2;
  u16* vbn   = (u16*)ws; ws += (size_t)4096 * 1024 * 2;
  u16* aout  = (u16*)ws; ws += (size_t)4096 * 1024 * 2;

  cvt_bf16<<<2048, 256, 0, stream>>>(x, xb, 524288);
  cvt_w4T<<<dim3(16, 16, 4), 256, 0, stream>>>(Wq, Wk, Wv, Wo, wqkvT, woT);
  cvt_xl_k<<<2048, 256, 0, stream>>>(xl, kt);
  cvt_xl_vT<<<1024, 256, 0, stream>>>(xl, vt);

  gemm128<0><<<32 * 24, 256, 0, stream>>>(xb, wqkvT, bq, bk, bv,
                                          qbuf, kvout, kt, vbn, nullptr, 24, 1024);
  trans_vnew<<<1024, 256, 0, stream>>>(vbn, vt);
  attn_kernel<<<1024, 256, 0, stream>>>(qbuf, kt, vt, rel, aout);
  gemm128<1><<<32 * 8, 256, 0, stream>>>(aout, woT, bo, nullptr, nullptr,
                                         nullptr, nullptr, nullptr, nullptr, out, 8, 1024);
}

// Round 3
// 218.561 us; speedup vs baseline: 1.4201x; 1.2737x over previous
//
#include <hip/hip_runtime.h>
#include <hip/hip_bf16.h>

typedef unsigned short u16;
typedef unsigned int u32;
typedef __attribute__((ext_vector_type(8))) short short8;
typedef __attribute__((ext_vector_type(4))) float f32x4;

#define B_ 4
#define T_ 1024
#define E_ 1024
#define NH 16
#define HD 1024
#define JTOT 2048
#define SCALE 0.125f
#define LOG2E 1.44269504f

// ---------- helpers ----------
__device__ __forceinline__ u16 f2b(float f) {
  u32 x = __float_as_uint(f);
  u32 r = (x + 0x7fffu + ((x >> 16) & 1u)) >> 16;  // RNE
  return (u16)r;
}
__device__ __forceinline__ u16 f2b_fast(float f) {  // round-half-up (2 ops)
  return (u16)((__float_as_uint(f) + 0x8000u) >> 16);
}
__device__ __forceinline__ float fexp2(float x) {
  float r;
  asm("v_exp_f32 %0, %1" : "=v"(r) : "v"(x));
  return r;
}

__device__ __forceinline__ void gload_lds16(const void* g, void* l) {
  __builtin_amdgcn_global_load_lds((const __attribute__((address_space(1))) u32*)g,
                                   (__attribute__((address_space(3))) u32*)l, 16, 0, 0);
}

__device__ __forceinline__ short8 pack8(float4 f0, float4 f1) {
  short8 o;
  o[0] = (short)f2b(f0.x); o[1] = (short)f2b(f0.y);
  o[2] = (short)f2b(f0.z); o[3] = (short)f2b(f0.w);
  o[4] = (short)f2b(f1.x); o[5] = (short)f2b(f1.y);
  o[6] = (short)f2b(f1.z); o[7] = (short)f2b(f1.w);
  return o;
}

// ---------- conversion kernels ----------
__global__ __launch_bounds__(256) void cvt_bf16(const float* __restrict__ in,
                                                u16* __restrict__ out, int n8) {
  int i = blockIdx.x * 256 + threadIdx.x;
  if (i >= n8) return;
  const float4* p = (const float4*)in + (size_t)i * 2;
  ((short8*)out)[i] = pack8(p[0], p[1]);
}

// fused 4x: W [1024][1024] f32 -> WT bf16 transposed
__global__ __launch_bounds__(256) void cvt_w4T(const float* __restrict__ Wq, const float* __restrict__ Wk,
                                               const float* __restrict__ Wv, const float* __restrict__ Wo,
                                               u16* __restrict__ wqkvT, u16* __restrict__ woT) {
  __shared__ float tile[64][65];
  const float* W;
  u16* WT;
  int z = blockIdx.z;
  if (z == 0) { W = Wq; WT = wqkvT; }
  else if (z == 1) { W = Wk; WT = wqkvT + (size_t)1024 * 1024; }
  else if (z == 2) { W = Wv; WT = wqkvT + (size_t)2048 * 1024; }
  else { W = Wo; WT = woT; }
  int t = threadIdx.x;
  int r0 = blockIdx.y * 64, c0 = blockIdx.x * 64;
#pragma unroll
  for (int i = 0; i < 16; ++i) {
    int r = i * 4 + (t >> 6), c = t & 63;
    tile[r][c] = W[(size_t)(r0 + r) * 1024 + c0 + c];
  }
  __syncthreads();
#pragma unroll
  for (int i = 0; i < 16; ++i) {
    int r = i * 4 + (t >> 6), c = t & 63;
    WT[(size_t)(c0 + r) * 1024 + r0 + c] = f2b(tile[c][r]);
  }
}

// xl k-half -> kt tiles [B][H][jc 0..15][64 j][64 d ^ swz] bf16
__global__ __launch_bounds__(256) void cvt_xl_k(const float* __restrict__ xl, u16* __restrict__ kt) {
  int i = blockIdx.x * 256 + threadIdx.x;  // [0, 524288)
  int hd8 = i & 127, j = (i >> 7) & 1023, b = i >> 17;
  const float4* p = (const float4*)(xl + ((((size_t)b * 1024 + j) * 2 + 0) * 1024 + (size_t)hd8 * 8));
  short8 o = pack8(p[0], p[1]);
  int h = hd8 >> 3, d0 = (hd8 & 7) * 8;
  int jc = j >> 6, jl = j & 63;
  u16* dst = kt + (((size_t)(b * 16 + h) * 32 + jc) * 4096) + jl * 64 + (d0 ^ (((jl >> 2) & 3) << 4));
  *(short8*)dst = o;
}

// xl v-half -> vt tiles [B][H][jc 0..15][64 d][64 j ^ swz] bf16 (transposed)
__global__ __launch_bounds__(256) void cvt_xl_vT(const float* __restrict__ xl, u16* __restrict__ vt) {
  __shared__ u16 Vl[64 * 72];
  int bx = blockIdx.x;
  int jc = bx & 15, h = (bx >> 4) & 15, b = bx >> 8;
  int t = threadIdx.x;
  int j0 = jc * 64;
#pragma unroll
  for (int it = 0; it < 2; ++it) {
    int p = t + 256 * it;
    int j = p >> 3, d8 = p & 7;
    const float4* src = (const float4*)(xl + ((((size_t)b * 1024 + j0 + j) * 2 + 1) * 1024 + h * 64 + (size_t)d8 * 8));
    *(short8*)&Vl[j * 72 + d8 * 8] = pack8(src[0], src[1]);
  }
  __syncthreads();
#pragma unroll
  for (int it = 0; it < 2; ++it) {
    int p = t + 256 * it;
    int d = p >> 3, j8 = p & 7;
    short8 o;
#pragma unroll
    for (int e = 0; e < 8; ++e) o[e] = (short)Vl[(j8 * 8 + e) * 72 + d];
    u16* dst = vt + (((size_t)(b * 16 + h) * 32 + jc) * 4096) + d * 64 + ((j8 * 8) ^ (((d >> 2) & 3) << 4));
    *(short8*)dst = o;
  }
}

// vb_new [b][tt][hd] bf16 -> vt tiles jc 16..31 (transposed + swizzled)
__global__ __launch_bounds__(256) void trans_vnew(const u16* __restrict__ vb, u16* __restrict__ vt) {
  __shared__ u16 Vl[64 * 72];
  int bx = blockIdx.x;
  int jcl = bx & 15, h = (bx >> 4) & 15, b = bx >> 8;
  int jc = 16 + jcl;
  int t = threadIdx.x;
  int t0 = jcl * 64;  // token base within [0,1024)
#pragma unroll
  for (int it = 0; it < 2; ++it) {
    int p = t + 256 * it;
    int j = p >> 3, d8 = p & 7;
    *(short8*)&Vl[j * 72 + d8 * 8] =
        *(const short8*)&vb[((size_t)b * 1024 + t0 + j) * 1024 + h * 64 + d8 * 8];
  }
  __syncthreads();
#pragma unroll
  for (int it = 0; it < 2; ++it) {
    int p = t + 256 * it;
    int d = p >> 3, j8 = p & 7;
    short8 o;
#pragma unroll
    for (int e = 0; e < 8; ++e) o[e] = (short)Vl[(j8 * 8 + e) * 72 + d];
    u16* dst = vt + (((size_t)(b * 16 + h) * 32 + jc) * 4096) + d * 64 + ((j8 * 8) ^ (((d >> 2) & 3) << 4));
    *(short8*)dst = o;
  }
}

// ---------- 128x128 bf16 MFMA GEMM, MODE 0 = QKV, MODE 1 = out-proj ----------
template <int MODE>
__global__ __launch_bounds__(256) void gemm128(
    const u16* __restrict__ A, const u16* __restrict__ BT,
    const float* __restrict__ b0, const float* __restrict__ b1, const float* __restrict__ b2,
    u16* __restrict__ qb, float* __restrict__ kvout, u16* __restrict__ kt, u16* __restrict__ vb,
    float* __restrict__ outf, int Ntiles, int Kdim) {
  __shared__ __align__(16) u16 As[128 * 32];
  __shared__ __align__(16) u16 Bs[128 * 32];
  const int t = threadIdx.x;
  const int lane = t & 63, wv = t >> 6;
  const int wr = wv >> 1, wc = wv & 1;
  const int m0 = (blockIdx.x / Ntiles) * 128;
  const int n0 = (blockIdx.x % Ntiles) * 128;
  const int lr = lane & 15, lg = lane >> 4;

  f32x4 acc[4][4] = {};

  for (int kc = 0; kc < Kdim; kc += 32) {
    __syncthreads();
#pragma unroll
    for (int i = 0; i < 2; ++i) {
      int p = t + 256 * i;
      gload_lds16(A + (size_t)(m0 + (p >> 2)) * Kdim + kc + (p & 3) * 8, &As[p * 8]);
    }
#pragma unroll
    for (int i = 0; i < 2; ++i) {
      int p = t + 256 * i;
      gload_lds16(BT + (size_t)(n0 + (p >> 2)) * Kdim + kc + (p & 3) * 8, &Bs[p * 8]);
    }
    __syncthreads();

    short8 af[4], bf[4];
#pragma unroll
    for (int mf = 0; mf < 4; ++mf)
      af[mf] = *(const short8*)&As[(wr * 64 + mf * 16 + lr) * 32 + lg * 8];
#pragma unroll
    for (int nf = 0; nf < 4; ++nf)
      bf[nf] = *(const short8*)&Bs[(wc * 64 + nf * 16 + lr) * 32 + lg * 8];
#pragma unroll
    for (int mf = 0; mf < 4; ++mf)
#pragma unroll
      for (int nf = 0; nf < 4; ++nf)
        acc[mf][nf] = __builtin_amdgcn_mfma_f32_16x16x32_bf16(af[mf], bf[nf], acc[mf][nf], 0, 0, 0);
  }

#pragma unroll
  for (int mf = 0; mf < 4; ++mf) {
#pragma unroll
    for (int nf = 0; nf < 4; ++nf) {
#pragma unroll
      for (int r = 0; r < 4; ++r) {
        int row = m0 + wr * 64 + mf * 16 + lg * 4 + r;
        int col = n0 + wc * 64 + nf * 16 + lr;
        float v = acc[mf][nf][r];
        if (MODE == 0) {
          int b = row >> 10, tt = row & 1023;
          if (col < 1024) {
            v += b0[col];
            qb[(size_t)row * HD + col] = f2b(v * (SCALE * SCALE * LOG2E));  // scales + log2e folded
          } else if (col < 2048) {
            int hd = col - 1024;
            v += b1[hd];
            kvout[((size_t)(b * 1024 + tt) * 2 + 0) * HD + hd] = v;
            int h = hd >> 6, d = hd & 63, jl = tt & 63, jc = 16 + (tt >> 6);
            kt[(((size_t)(b * 16 + h) * 32 + jc) * 4096) + jl * 64 + (d ^ (((jl >> 2) & 3) << 4))] = f2b(v);
          } else {
            int hd = col - 2048;
            v += b2[hd];
            kvout[((size_t)(b * 1024 + tt) * 2 + 1) * HD + hd] = v;
            vb[((size_t)b * 1024 + tt) * 1024 + hd] = f2b(v);
          }
        } else {
          outf[(size_t)row * E_ + col] = v + b0[col];
        }
      }
    }
  }
}

// ---------- flash attention: block = (b, h, 64-row q-tile), 4 waves x 16 rows ----------
__global__ __launch_bounds__(256) void attn_kernel(
    const u16* __restrict__ qb, const u16* __restrict__ kt, const u16* __restrict__ vt,
    const float* __restrict__ rel, u16* __restrict__ aout) {
  __shared__ __align__(16) u16 Ks[2][4096];
  __shared__ __align__(16) u16 Vs[2][4096];
  __shared__ __align__(16) u16 Pl[4096];
  const int bx = blockIdx.x;
  // qt in HIGH bits: co-resident blocks (bx, bx+256, ...) get qts {q,q+4,q+8,q+12} -> balanced CUs
  const int b = bx & 3, h = (bx >> 2) & 15, qt = bx >> 6;
  const int i0 = qt * 64;
  const int t = threadIdx.x, lane = t & 63, w = t >> 6;
  const int lr = lane & 15, lg = lane >> 4;
  const int sel = (lr >> 2) & 3;
  const float RC = SCALE * LOG2E;  // rel coefficient (log2 domain)

  const u16* ktb = kt + (size_t)(b * 16 + h) * 32 * 4096;
  const u16* vtb = vt + (size_t)(b * 16 + h) * 32 * 4096;
  const float* relbase = rel + (size_t)h * T_ * JTOT;
  const int ib = i0 + w * 16 + lg * 4;

  short8 qf[2];
#pragma unroll
  for (int kc = 0; kc < 2; ++kc)
    qf[kc] = *(const short8*)&qb[(size_t)(b * T_ + i0 + w * 16 + lr) * HD + h * 64 + kc * 32 + lg * 8];

  // ones B-frag for row-sum MFMA: B^T row 0 = 1.0, rows 1..15 = 0
  short8 vf5;
#pragma unroll
  for (int e = 0; e < 8; ++e) vf5[e] = (lr == 0) ? (short)0x3f80 : (short)0;

  const int nchunks = qt + 17;

  auto stage = [&](int buf, int jc2) {
    const u16* ksrc = ktb + (size_t)jc2 * 4096;
    const u16* vsrc = vtb + (size_t)jc2 * 4096;
    gload_lds16(ksrc + t * 8, &Ks[buf][t * 8]);
    gload_lds16(ksrc + (t + 256) * 8, &Ks[buf][(t + 256) * 8]);
    gload_lds16(vsrc + t * 8, &Vs[buf][t * 8]);
    gload_lds16(vsrc + (t + 256) * 8, &Vs[buf][(t + 256) * 8]);
  };

  float rl[4][4];
  auto loadrel = [&](int j0) {
#pragma unroll
    for (int nf = 0; nf < 4; ++nf)
#pragma unroll
      for (int r = 0; r < 4; ++r)
        rl[nf][r] = relbase[(size_t)(ib + r) * JTOT + j0 + nf * 16 + lr];
  };

  stage(0, 0);
  loadrel(0);

  f32x4 o[5] = {};  // o[4] = running row-sum (col 64, lives in lanes lr==0)
  float mrow[4];
#pragma unroll
  for (int r = 0; r < 4; ++r) mrow[r] = -__builtin_inff();

  int cur = 0;
  for (int jc = 0; jc < nchunks; ++jc) {
    __syncthreads();  // drains own vmcnt -> Ks/Vs[cur] staged; waves aligned
    if (jc + 1 < nchunks) stage(cur ^ 1, jc + 1);

    // S = Q K^T (log2 domain: q pre-scaled by SCALE^2*log2e)
    f32x4 s4[4] = {};
#pragma unroll
    for (int nf = 0; nf < 4; ++nf)
#pragma unroll
      for (int kc = 0; kc < 2; ++kc) {
        short8 kf = *(const short8*)&Ks[cur][(nf * 16 + lr) * 64 + ((kc * 32 + lg * 8) ^ (sel << 4))];
        s4[nf] = __builtin_amdgcn_mfma_f32_16x16x32_bf16(qf[kc], kf, s4[nf], 0, 0, 0);
      }

    // logits + in-lane max
    float p[4][4], lmax[4];
    const bool domask = (jc == qt + 16);
#pragma unroll
    for (int nf = 0; nf < 4; ++nf)
#pragma unroll
      for (int r = 0; r < 4; ++r) {
        float v = fmaf(rl[nf][r], RC, s4[nf][r]);
        if (domask && (nf * 16 + lr) > (w * 16 + lg * 4 + r)) v = -__builtin_inff();
        p[nf][r] = v;
      }
#pragma unroll
    for (int r = 0; r < 4; ++r)
      lmax[r] = fmaxf(fmaxf(p[0][r], p[1][r]), fmaxf(p[2][r], p[3][r]));
    if (jc + 1 < nchunks) loadrel((jc + 1) * 64);  // issue early, consumed next iter

    // defer-max: cross-lane tree only when a rescale is actually needed
    float need = -__builtin_inff();
#pragma unroll
    for (int r = 0; r < 4; ++r) need = fmaxf(need, lmax[r] - mrow[r]);
    const bool dores = !__all(need <= 11.0f);
    if (dores) {
      float chmax[4], sc[4];
#pragma unroll
      for (int r = 0; r < 4; ++r) chmax[r] = lmax[r];
#pragma unroll
      for (int msk = 1; msk <= 8; msk <<= 1)
#pragma unroll
        for (int r = 0; r < 4; ++r)
          chmax[r] = fmaxf(chmax[r], __shfl_xor(chmax[r], msk, 64));
#pragma unroll
      for (int r = 0; r < 4; ++r) {
        float nm = fmaxf(mrow[r], chmax[r]);
        sc[r] = fexp2(mrow[r] - nm);
        mrow[r] = nm;
      }
#pragma unroll
      for (int nf = 0; nf < 5; ++nf)
#pragma unroll
        for (int r = 0; r < 4; ++r) o[nf][r] *= sc[r];
    }

    // P = exp2(p - m), store bf16 to wave-private swizzled LDS
#pragma unroll
    for (int nf = 0; nf < 4; ++nf)
#pragma unroll
      for (int r = 0; r < 4; ++r) {
        float pe = fexp2(p[nf][r] - mrow[r]);
        Pl[(w * 16 + lg * 4 + r) * 64 + (((nf ^ lg) << 4) + lr)] = f2b_fast(pe);
      }

    // O += P @ V; extra ones-block MFMA accumulates the row-sum into o[4]
#pragma unroll
    for (int kc = 0; kc < 2; ++kc) {
      const int pcol = (kc * 32 + lg * 8) ^ (sel << 4);
      short8 pa = *(const short8*)&Pl[(w * 16 + lr) * 64 + pcol];
#pragma unroll
      for (int nf = 0; nf < 4; ++nf) {
        short8 vf = *(const short8*)&Vs[cur][(nf * 16 + lr) * 64 + pcol];
        o[nf] = __builtin_amdgcn_mfma_f32_16x16x32_bf16(pa, vf, o[nf], 0, 0, 0);
      }
      o[4] = __builtin_amdgcn_mfma_f32_16x16x32_bf16(pa, vf5, o[4], 0, 0, 0);
    }
    cur ^= 1;
  }

  // row-sum lives in lanes lr==0 of each lg group: broadcast, normalize, store
  float inv[4];
#pragma unroll
  for (int r = 0; r < 4; ++r)
    inv[r] = 1.0f / __shfl(o[4][r], lane & 48, 64);
#pragma unroll
  for (int nf = 0; nf < 4; ++nf)
#pragma unroll
    for (int r = 0; r < 4; ++r) {
      int i = i0 + w * 16 + lg * 4 + r, d = nf * 16 + lr;
      aout[(size_t)(b * T_ + i) * HD + h * 64 + d] = f2b_fast(o[nf][r] * inv[r]);
    }
}

// ---------- launch ----------
extern "C" void kernel_launch(void* const* d_in, const int* in_sizes, int n_in,
                              void* d_out, int out_size, void* d_ws, size_t ws_size,
                              hipStream_t stream) {
  const float* x  = (const float*)d_in[0];
  const float* xl = (const float*)d_in[1];
  const float* rel = (const float*)d_in[2];
  const float* Wq = (const float*)d_in[3];
  const float* bq = (const float*)d_in[4];
  const float* Wk = (const float*)d_in[5];
  const float* bk = (const float*)d_in[6];
  const float* Wv = (const float*)d_in[7];
  const float* bv = (const float*)d_in[8];
  const float* Wo = (const float*)d_in[9];
  const float* bo = (const float*)d_in[10];

  float* out = (float*)d_out;
  float* kvout = out + (size_t)B_ * T_ * E_;

  char* ws = (char*)d_ws;
  u16* xb    = (u16*)ws; ws += (size_t)4096 * 1024 * 2;
  u16* wqkvT = (u16*)ws; ws += (size_t)3072 * 1024 * 2;
  u16* woT   = (u16*)ws; ws += (size_t)1024 * 1024 * 2;
  u16* qbuf  = (u16*)ws; ws += (size_t)4096 * 1024 * 2;
  u16* kt    = (u16*)ws; ws += (size_t)B_ * NH * 32 * 4096 * 2;
  u16* vt    = (u16*)ws; ws += (size_t)B_ * NH * 32 * 4096 * 2;
  u16* vbn   = (u16*)ws; ws += (size_t)4096 * 1024 * 2;
  u16* aout  = (u16*)ws; ws += (size_t)4096 * 1024 * 2;

  cvt_bf16<<<2048, 256, 0, stream>>>(x, xb, 524288);
  cvt_w4T<<<dim3(16, 16, 4), 256, 0, stream>>>(Wq, Wk, Wv, Wo, wqkvT, woT);
  cvt_xl_k<<<2048, 256, 0, stream>>>(xl, kt);
  cvt_xl_vT<<<1024, 256, 0, stream>>>(xl, vt);

  gemm128<0><<<32 * 24, 256, 0, stream>>>(xb, wqkvT, bq, bk, bv,
                                          qbuf, kvout, kt, vbn, nullptr, 24, 1024);
  trans_vnew<<<1024, 256, 0, stream>>>(vbn, vt);
  attn_kernel<<<1024, 256, 0, stream>>>(qbuf, kt, vt, rel, aout);
  gemm128<1><<<32 * 8, 256, 0, stream>>>(aout, woT, bo, nullptr, nullptr,
                                         nullptr, nullptr, nullptr, nullptr, out, 8, 1024);
}